// Round 5
// baseline (213.784 us; speedup 1.0000x reference)
//
#include <hip/hip_runtime.h>

#define WEIGHT 0.1f
#define THRESH 0.3f
#define MARGIN 0.1f

#define NTHREADS 256
#define ROWS_PER_BATCH 8
#define NBATCH 2
#define ROWS_PER_THREAD (ROWS_PER_BATCH * NBATCH)       // 16
#define ROWS_PER_BLOCK (NTHREADS * ROWS_PER_THREAD)     // 4096

// d_ws layout: [0 .. nblocks) doubles = per-block totals, then nblocks uints.
// Every launch writes ALL slots (grid fixed by n), so 0xAA poison is harmless.

__device__ __forceinline__ void row_terms(float4 p, float t,
                                          float& acc, unsigned int& cnt) {
    bool g4 = p.y > THRESH;
    bool g5 = p.z > THRESH;
    bool g6 = p.w > THRESH;
    bool m45  = g4 && g5;
    bool m56  = g5 && g6;
    bool m456 = m45 && g6;

    float term45 = fmaxf(MARGIN - (p.z * t - p.y * t), 0.0f);
    float term56 = fmaxf(MARGIN - (p.w * t - p.z * t), 0.0f);
    float d45 = fabsf(p.z - p.y);
    float d56 = fabsf(p.w - p.z);
    float torder = fmaxf(d45 - d56 + MARGIN, 0.0f);

    acc += (m45  ? term45 : 0.0f)
         + (m56  ? term56 : 0.0f)
         + (m456 ? torder : 0.0f);
    cnt += (unsigned)m45 + (unsigned)m56 + (unsigned)m456;
}

__global__ __launch_bounds__(NTHREADS) void tc_main_kernel(
        const float4* __restrict__ pred,
        const float*  __restrict__ times,
        double*       __restrict__ blk_tot,
        unsigned int* __restrict__ blk_cnt,
        int n) {
    float local = 0.0f;
    unsigned int cnt = 0;

    const int  tid       = threadIdx.x;
    const long blockBase = (long)blockIdx.x * ROWS_PER_BLOCK;

    if (blockBase + ROWS_PER_BLOCK <= (long)n) {
        // Software-pipelined two-batch body. Every load instruction is
        // wave-contiguous (pred dwordx4 -> 1KB/instr, times dword -> 256B/instr).
        float4 pA[ROWS_PER_BATCH], pB[ROWS_PER_BATCH];
        float  tA[ROWS_PER_BATCH], tB[ROWS_PER_BATCH];

        const long bA = blockBase;                                  // rows 0..2047 of block
        const long bB = blockBase + (long)ROWS_PER_BATCH * NTHREADS; // rows 2048..4095

        // Issue batch A loads
#pragma unroll
        for (int r = 0; r < ROWS_PER_BATCH; ++r)
            pA[r] = pred[bA + (long)r * NTHREADS + tid];
#pragma unroll
        for (int r = 0; r < ROWS_PER_BATCH; ++r)
            tA[r] = times[bA + (long)r * NTHREADS + tid];

        // Issue batch B loads BEFORE consuming batch A: memory pipe stays fed
        // while we compute on A.
#pragma unroll
        for (int r = 0; r < ROWS_PER_BATCH; ++r)
            pB[r] = pred[bB + (long)r * NTHREADS + tid];
#pragma unroll
        for (int r = 0; r < ROWS_PER_BATCH; ++r)
            tB[r] = times[bB + (long)r * NTHREADS + tid];

        // Compute A (compiler waits only on A's vmcnt slice), then B.
#pragma unroll
        for (int r = 0; r < ROWS_PER_BATCH; ++r)
            row_terms(pA[r], tA[r], local, cnt);
#pragma unroll
        for (int r = 0; r < ROWS_PER_BATCH; ++r)
            row_terms(pB[r], tB[r], local, cnt);
    } else {
        for (long i = blockBase + tid; i < (long)n; i += NTHREADS)
            row_terms(pred[i], times[i], local, cnt);
    }

    // Wave-64 butterfly reduction (promote total to double for the tree)
    double dl = (double)local;
    for (int o = 32; o > 0; o >>= 1) {
        dl  += __shfl_down(dl, o, 64);
        cnt += __shfl_down(cnt, o, 64);
    }

    __shared__ double       s_tot[NTHREADS / 64];
    __shared__ unsigned int s_cnt[NTHREADS / 64];
    int wave = threadIdx.x >> 6;
    int lane = threadIdx.x & 63;
    if (lane == 0) { s_tot[wave] = dl; s_cnt[wave] = cnt; }
    __syncthreads();

    if (threadIdx.x == 0) {
        double bt = 0.0;
        unsigned int bc = 0;
        for (int w = 0; w < NTHREADS / 64; ++w) { bt += s_tot[w]; bc += s_cnt[w]; }
        blk_tot[blockIdx.x] = bt;     // distinct slot per block: no contention
        blk_cnt[blockIdx.x] = bc;
    }
}

__global__ __launch_bounds__(NTHREADS) void tc_finalize_kernel(
        const double*       __restrict__ blk_tot,
        const unsigned int* __restrict__ blk_cnt,
        float* __restrict__ out,
        int nblocks) {
    double dl = 0.0;
    unsigned long long cl = 0;
    for (int i = threadIdx.x; i < nblocks; i += NTHREADS) {
        dl += blk_tot[i];
        cl += blk_cnt[i];
    }
    for (int o = 32; o > 0; o >>= 1) {
        dl += __shfl_down(dl, o, 64);
        cl += __shfl_down(cl, o, 64);
    }
    __shared__ double             s_tot[NTHREADS / 64];
    __shared__ unsigned long long s_cnt[NTHREADS / 64];
    int wave = threadIdx.x >> 6;
    int lane = threadIdx.x & 63;
    if (lane == 0) { s_tot[wave] = dl; s_cnt[wave] = cl; }
    __syncthreads();
    if (threadIdx.x == 0) {
        double total = 0.0;
        unsigned long long count = 0;
        for (int w = 0; w < NTHREADS / 64; ++w) { total += s_tot[w]; count += s_cnt[w]; }
        double c = (double)count;
        double loss = (c > 0.0) ? (total / fmax(c, 1.0)) : total;
        out[0] = (float)((double)WEIGHT * loss);
    }
}

extern "C" void kernel_launch(void* const* d_in, const int* in_sizes, int n_in,
                              void* d_out, int out_size, void* d_ws, size_t ws_size,
                              hipStream_t stream) {
    const float4* pred  = (const float4*)d_in[0];  // (B,4) fp32 -> one float4/row
    const float*  times = (const float*)d_in[1];   // (B,1) fp32
    int n = in_sizes[1];                           // B = rows

    int nblocks = (n + ROWS_PER_BLOCK - 1) / ROWS_PER_BLOCK;   // 2048 for B=2^23

    double*       blk_tot = (double*)d_ws;
    unsigned int* blk_cnt = (unsigned int*)((char*)d_ws + (size_t)nblocks * sizeof(double));

    tc_main_kernel<<<nblocks, NTHREADS, 0, stream>>>(pred, times, blk_tot, blk_cnt, n);
    tc_finalize_kernel<<<1, NTHREADS, 0, stream>>>(blk_tot, blk_cnt, (float*)d_out, nblocks);
}

// Round 7
// 199.323 us; speedup vs baseline: 1.0726x; 1.0726x over previous
//
#include <hip/hip_runtime.h>

#define WEIGHT 0.1f
#define THRESH 0.3f
#define MARGIN 0.1f

#define NTHREADS 256
#define ROWS_PER_THREAD 8
#define ROWS_PER_BLOCK (NTHREADS * ROWS_PER_THREAD)   // 2048

// Native clang vector type: __builtin_nontemporal_load requires a real
// vector-of-float, not HIP's struct float4.
typedef float vfloat4 __attribute__((ext_vector_type(4)));

// d_ws layout: [0 .. nblocks) doubles = per-block totals, then nblocks uints.
// Every launch writes ALL slots (grid fixed by n), so 0xAA poison is harmless.
//
// KEY (R6/R7): the harness poison-fills 512 MiB of d_ws before every timed
// launch, leaving L2/L3 full of dirty lines and the input evicted to HBM.
// Allocating reads then force a 64B writeback per 64B read — halving
// effective read BW (the ~2.6 TB/s plateau of R2-R5). Non-temporal loads
// skip allocation => pure HBM read stream. Zero reuse => NT is also the
// semantically right policy.

__device__ __forceinline__ void row_terms(vfloat4 p, float t,
                                          float& acc, unsigned int& cnt) {
    // p[1]=p4, p[2]=p5, p[3]=p6 (p[0] unused)
    bool g4 = p.y > THRESH;
    bool g5 = p.z > THRESH;
    bool g6 = p.w > THRESH;
    bool m45  = g4 && g5;
    bool m56  = g5 && g6;
    bool m456 = m45 && g6;

    float term45 = fmaxf(MARGIN - (p.z * t - p.y * t), 0.0f);
    float term56 = fmaxf(MARGIN - (p.w * t - p.z * t), 0.0f);
    float d45 = fabsf(p.z - p.y);
    float d56 = fabsf(p.w - p.z);
    float torder = fmaxf(d45 - d56 + MARGIN, 0.0f);

    acc += (m45  ? term45 : 0.0f)
         + (m56  ? term56 : 0.0f)
         + (m456 ? torder : 0.0f);
    cnt += (unsigned)m45 + (unsigned)m56 + (unsigned)m456;
}

__global__ __launch_bounds__(NTHREADS) void tc_main_kernel(
        const vfloat4* __restrict__ pred,
        const float*   __restrict__ times,
        double*        __restrict__ blk_tot,
        unsigned int*  __restrict__ blk_cnt,
        int n) {
    float local = 0.0f;
    unsigned int cnt = 0;

    const int  tid       = threadIdx.x;
    const long blockBase = (long)blockIdx.x * ROWS_PER_BLOCK;

    if (blockBase + ROWS_PER_BLOCK <= (long)n) {
        // 16 independent, per-instruction-coalesced, NON-TEMPORAL loads
        // issued before any use.
        vfloat4 p[ROWS_PER_THREAD];
        float   t[ROWS_PER_THREAD];
#pragma unroll
        for (int r = 0; r < ROWS_PER_THREAD; ++r)
            p[r] = __builtin_nontemporal_load(&pred[blockBase + (long)r * NTHREADS + tid]);
#pragma unroll
        for (int r = 0; r < ROWS_PER_THREAD; ++r)
            t[r] = __builtin_nontemporal_load(&times[blockBase + (long)r * NTHREADS + tid]);
#pragma unroll
        for (int r = 0; r < ROWS_PER_THREAD; ++r)
            row_terms(p[r], t[r], local, cnt);
    } else {
        for (long i = blockBase + tid; i < (long)n; i += NTHREADS) {
            vfloat4 p = __builtin_nontemporal_load(&pred[i]);
            float   t = __builtin_nontemporal_load(&times[i]);
            row_terms(p, t, local, cnt);
        }
    }

    // Wave-64 butterfly reduction (promote total to double for the tree)
    double dl = (double)local;
    for (int o = 32; o > 0; o >>= 1) {
        dl  += __shfl_down(dl, o, 64);
        cnt += __shfl_down(cnt, o, 64);
    }

    __shared__ double       s_tot[NTHREADS / 64];
    __shared__ unsigned int s_cnt[NTHREADS / 64];
    int wave = threadIdx.x >> 6;
    int lane = threadIdx.x & 63;
    if (lane == 0) { s_tot[wave] = dl; s_cnt[wave] = cnt; }
    __syncthreads();

    if (threadIdx.x == 0) {
        double bt = 0.0;
        unsigned int bc = 0;
        for (int w = 0; w < NTHREADS / 64; ++w) { bt += s_tot[w]; bc += s_cnt[w]; }
        blk_tot[blockIdx.x] = bt;     // distinct slot per block: no contention
        blk_cnt[blockIdx.x] = bc;
    }
}

__global__ __launch_bounds__(NTHREADS) void tc_finalize_kernel(
        const double*       __restrict__ blk_tot,
        const unsigned int* __restrict__ blk_cnt,
        float* __restrict__ out,
        int nblocks) {
    double dl = 0.0;
    unsigned long long cl = 0;
    for (int i = threadIdx.x; i < nblocks; i += NTHREADS) {
        dl += blk_tot[i];
        cl += blk_cnt[i];
    }
    for (int o = 32; o > 0; o >>= 1) {
        dl += __shfl_down(dl, o, 64);
        cl += __shfl_down(cl, o, 64);
    }
    __shared__ double             s_tot[NTHREADS / 64];
    __shared__ unsigned long long s_cnt[NTHREADS / 64];
    int wave = threadIdx.x >> 6;
    int lane = threadIdx.x & 63;
    if (lane == 0) { s_tot[wave] = dl; s_cnt[wave] = cl; }
    __syncthreads();
    if (threadIdx.x == 0) {
        double total = 0.0;
        unsigned long long count = 0;
        for (int w = 0; w < NTHREADS / 64; ++w) { total += s_tot[w]; count += s_cnt[w]; }
        double c = (double)count;
        double loss = (c > 0.0) ? (total / fmax(c, 1.0)) : total;
        out[0] = (float)((double)WEIGHT * loss);
    }
}

extern "C" void kernel_launch(void* const* d_in, const int* in_sizes, int n_in,
                              void* d_out, int out_size, void* d_ws, size_t ws_size,
                              hipStream_t stream) {
    const vfloat4* pred  = (const vfloat4*)d_in[0];  // (B,4) fp32 -> one vfloat4/row
    const float*   times = (const float*)d_in[1];    // (B,1) fp32
    int n = in_sizes[1];                             // B = rows

    int nblocks = (n + ROWS_PER_BLOCK - 1) / ROWS_PER_BLOCK;   // 4096 for B=2^23

    double*       blk_tot = (double*)d_ws;
    unsigned int* blk_cnt = (unsigned int*)((char*)d_ws + (size_t)nblocks * sizeof(double));

    tc_main_kernel<<<nblocks, NTHREADS, 0, stream>>>(pred, times, blk_tot, blk_cnt, n);
    tc_finalize_kernel<<<1, NTHREADS, 0, stream>>>(blk_tot, blk_cnt, (float*)d_out, nblocks);
}